// Round 7
// baseline (194.627 us; speedup 1.0000x reference)
//
#include <hip/hip_runtime.h>
#include <math.h>

// Problem constants (fixed instance: bs=32, S=512, E=512, T=2048)
#define BS 32
#define S_TOK 512
#define E_DIM 512
#define T_FR 2048
#define FPB 8           // frames per output block (R4-best structure)
#define WMAX 20         // union-window clamp for 8 frames (typ ~6-11)
// exp cut: dropped softmax terms < e^-25 of the max term (output perturbation
// ~1e-10 abs; absmax 0.0156 is the bf16-grain ref-rounding floor).
#define THRESH -25.0f

// NOTE: durations never zero -> reference's MASK_FILL branch is identity.

// ROUND 6 POST-MORTEM: persistent de-phased blocks (traffic-identical to R4)
// were WORSE (171.0 vs 165.6) -> store-burst/lockstep theory falsified (twice,
// with R5). R4 remains best. Six rounds moved net -7us; two stories remain:
//  (a) kernel ~45us (near its ~32us floor) + ~110-120us harness tax
//      (79us poison fill + dozens of tiny reset() restore dispatches);
//  (b) kernel ~75-80us (hiding just under the 78us fills in top-5) with an
//      unidentified occupancy-independent internal limiter.
// Occupancy evidence (R2->R4: 4x occupancy, only -4us) favors (a) but can't
// close it: our kernel's own counters have never been visible.
// ROUND 7: DECOMPOSITION PROBE. Launch the unmodified R4 kernel TWICE
// (idempotent: output is a pure function of inputs; no workspace/global state).
// K = dur_us(this round) - 165.6 is the kernel's true steady-state duration.
// Pre-committed: K<=55 -> revert to single launch, declare roofline with
// accounting; K>=65 -> internal-stall story confirmed, attack with the
// now-visible fused_all counters (it will enter top-5 if K>~78).

typedef float vfloat4 __attribute__((ext_vector_type(4)));

__global__ __launch_bounds__(256, 8) void fused_all(
    const float* __restrict__ emb,
    const float* __restrict__ dur,
    const float* __restrict__ log_sigma,
    float* __restrict__ x,
    float* __restrict__ mask_out) {
  // XCD swizzle: 8192 blocks; id&7 = XCD slot -> 1024 contiguous-t blocks
  // per XCD = 4 whole batches (4 MB emb slice = its L2).
  int id = blockIdx.x;
  int sw = ((id & 7) << 10) + (id >> 3);
  int b = sw >> 8;             // 256 blocks per batch
  int t0 = (sw & 255) << 3;    // * FPB

  int tid = threadIdx.x;
  int grp = tid >> 7;          // frame group: 0 -> frames t0+0..3, 1 -> t0+4..7
  int col = tid & 127;         // vfloat4 column owner (E_DIM/4 = 128)

  __shared__ float cbS[S_TOK];               // centers, 2 KB
  __shared__ __align__(16) float wT[WMAX][FPB];  // raw exp weights, 640 B
  __shared__ float mS[FPB];                  // per-frame max
  __shared__ float invS[FPB];                // per-frame 1/sum
  __shared__ double wsumS[4];
  __shared__ int histS[FPB];                 // bucket f = #centers in [tq_{f-1},tq_f)
  __shared__ int n0S[4];                     // per-wave partials of count(c < tq0)
  __shared__ int uloS, cntS;
  __shared__ float totalS;

  if (tid < FPB) histS[tid] = 0;

  float inv_sigma = expf(-log_sigma[0]);
  float tq0 = (float)t0 + 0.5f;
  float tq7 = (float)t0 + 7.5f;

  // ---- stage 1: fp64 cumsum of this batch's durations (redundant/block) ----
  {
    const float* dp = dur + b * S_TOK;
    int i2 = tid << 1;
    double d0 = (double)dp[i2];
    double d1 = (double)dp[i2 + 1];
    double pair = d0 + d1;
    double run = pair;                  // wave-inclusive scan of pair sums
#pragma unroll
    for (int off = 1; off < 64; off <<= 1) {
      double v = __shfl_up(run, off, 64);
      if ((tid & 63) >= off) run += v;
    }
    int w = tid >> 6;
    if ((tid & 63) == 63) wsumS[w] = run;
    __syncthreads();   // covers wsumS AND histS zero-init
    double wexcl = 0.0;
#pragma unroll
    for (int k = 0; k < 3; ++k) wexcl += (k < w) ? wsumS[k] : 0.0;
    double incl = wexcl + run;          // inclusive cumsum through this pair
    double excl = incl - pair;          // exclusive before this pair
    float c0 = (float)(excl + d0 - 0.5 * d0);
    float c1 = (float)(excl + (d0 + d1) - 0.5 * d1);
    cbS[i2] = c0;
    cbS[i2 + 1] = c1;

    // insertion-index machinery: N_f = count(c < tq_f) = N0 + prefix_hist.
    // Only in-range centers (~2-3 per block) touch atomics.
    int n0 = (c0 < tq0 ? 1 : 0) + (c1 < tq0 ? 1 : 0);
    if (c0 >= tq0 && c0 < tq7) atomicAdd(&histS[(int)floorf(c0 - tq0) + 1], 1);
    if (c1 >= tq0 && c1 < tq7) atomicAdd(&histS[(int)floorf(c1 - tq0) + 1], 1);
#pragma unroll
    for (int off = 1; off < 64; off <<= 1) n0 += __shfl_xor(n0, off, 64);
    if ((tid & 63) == 0) n0S[w] = n0;
    if (tid == 255) totalS = (float)incl;
  }
  __syncthreads();   // cbS, histS, n0S ready

  // ---- stage 2 (wave 0, fully parallel) ----
  if (tid < 64) {
    int l = tid;
    // inclusive scan of hist over lanes 0..7 (lane 0 -> 0)
    int sc = (l >= 1 && l < FPB) ? histS[l] : 0;
#pragma unroll
    for (int off = 1; off < FPB; off <<= 1) {
      int v = __shfl_up(sc, off, 64);
      if (l >= off) sc += v;
    }
    int N0 = n0S[0] + n0S[1] + n0S[2] + n0S[3];
    int best = 0;
    float m = 0.0f;
    if (l < FPB) {
      int N = N0 + sc;             // insertion index for frame l
      float tqf = (float)(t0 + l) + 0.5f;
      if (N <= 0) {
        best = 0;
        float z = (tqf - cbS[0]) * inv_sigma; m = -0.5f * z * z;
      } else if (N >= S_TOK) {
        best = S_TOK - 1;
        float z = (tqf - cbS[best]) * inv_sigma; m = -0.5f * z * z;
      } else {
        float za = (tqf - cbS[N - 1]) * inv_sigma; float va = -0.5f * za * za;
        float zb = (tqf - cbS[N]) * inv_sigma;     float vb = -0.5f * zb * zb;
        if (va >= vb) { best = N - 1; m = va; } else { best = N; m = vb; }
      }
      mS[l] = m;
    }
    // union window edges: frame 0 lower, frame 7 upper (edges monotone in f);
    // 16-lane ballot probe each (extent ~2-3 tokens; flags monotone).
    int best0 = __shfl(best, 0, 64);  float m0 = __shfl(m, 0, 64);
    int best7 = __shfl(best, 7, 64);  float m7 = __shfl(m, 7, 64);
    int p = l & 15;
    bool flag = false;
    if (l < 16) {
      int s = best0 - 1 - p;
      if (s >= 0) {
        float z = (tq0 - cbS[s]) * inv_sigma;
        flag = (-0.5f * z * z) > m0 + THRESH;
      }
    } else if (l < 32) {
      int s = best7 + 1 + p;
      if (s < S_TOK) {
        float z = (tq7 - cbS[s]) * inv_sigma;
        flag = (-0.5f * z * z) > m7 + THRESH;
      }
    }
    unsigned long long bal = __ballot(flag);
    if (l == 0) {
      int wl = best0 - __popcll(bal & 0xFFFFull);
      int wh = best7 + __popcll(bal & 0xFFFF0000ull);
      uloS = wl;
      cntS = min(wh - wl + 1, WMAX);  // clamp = memory-safety only
    }
  }
  __syncthreads();

  int ulo = uloS, cnt = cntS;

  // prefetch first two emb rows NOW; latency hides under the weights pass
  const vfloat4* e4 =
      (const vfloat4*)emb + ((size_t)(b * S_TOK + ulo)) * (E_DIM / 4) + col;
  vfloat4 vcur = e4[0];
  vfloat4 vnext = e4[(size_t)min(1, cnt - 1) * (E_DIM / 4)];

  // ---- weights: raw exp(v - m_f); cnt*8 <= 160 items -> single pass ----
  if (tid < cnt * FPB) {
    int i = tid >> 3, f = tid & 7;
    float c = cbS[ulo + i];
    float tqf = (float)(t0 + f) + 0.5f;
    float z = (tqf - c) * inv_sigma;
    float v = -0.5f * z * z;
    wT[i][f] = expf(v - mS[f]);   // v<=m always -> exp in (0,1]
  }
  __syncthreads();

  // ---- per-frame sums (32 lanes per frame), 1/l into invS ----
  {
    int f = tid >> 5, p = tid & 31;
    float s = 0.0f;
    for (int i = p; i < cnt; i += 32) s += wT[i][f];
#pragma unroll
    for (int off = 1; off < 32; off <<= 1) s += __shfl_xor(s, off, 64);
    if (p == 0) invS[f] = 1.0f / s;   // s >= exp(0)=1 (best token in union)
  }
  __syncthreads();

  // ---- sparse weighted sum: 4 vfloat4 accumulators, depth-2 prefetch ----
  vfloat4 acc0 = {0.f,0.f,0.f,0.f}, acc1 = {0.f,0.f,0.f,0.f};
  vfloat4 acc2 = {0.f,0.f,0.f,0.f}, acc3 = {0.f,0.f,0.f,0.f};

  for (int i = 0; i < cnt; ++i) {
    vfloat4 vfut = e4[(size_t)min(i + 2, cnt - 1) * (E_DIM / 4)];
    vfloat4 w = *(const vfloat4*)&wT[i][grp << 2];  // broadcast read
    acc0 += w.x * vcur;
    acc1 += w.y * vcur;
    acc2 += w.z * vcur;
    acc3 += w.w * vcur;
    vcur = vnext; vnext = vfut;
  }

  // Regular cached stores; normalization (1/l_f) folded in here.
  int f0 = grp << 2;
  vfloat4* xp = (vfloat4*)x +
      ((size_t)(b * T_FR + t0 + f0)) * (E_DIM / 4) + col;
  xp[0 * (E_DIM / 4)] = acc0 * invS[f0 + 0];
  xp[1 * (E_DIM / 4)] = acc1 * invS[f0 + 1];
  xp[2 * (E_DIM / 4)] = acc2 * invS[f0 + 2];
  xp[3 * (E_DIM / 4)] = acc3 * invS[f0 + 3];

  if (tid < FPB) {
    int t = t0 + tid;
    mask_out[b * T_FR + t] = ((float)t < totalS) ? 1.0f : 0.0f;
  }
}

// ---------------------------------------------------------------------------
extern "C" void kernel_launch(void* const* d_in, const int* in_sizes, int n_in,
                              void* d_out, int out_size, void* d_ws,
                              size_t ws_size, hipStream_t stream) {
  const float* emb = (const float*)d_in[0];        // (32, 512, 512)
  const float* dur = (const float*)d_in[1];        // (32, 512)
  const float* log_sigma = (const float*)d_in[2];  // (1,)

  float* x = (float*)d_out;                         // (32, 2048, 512)
  float* mask_out = x + (size_t)BS * T_FR * E_DIM;  // (32, 2048)

  // MEASUREMENT ROUND: launch the identical kernel twice (idempotent — pure
  // function of inputs). dur_us - 165.6 = steady-state kernel duration K.
  // Second launch runs with warm L2 -> K is a (tight) lower bound.
  fused_all<<<(BS * T_FR) / FPB, 256, 0, stream>>>(
      emb, dur, log_sigma, x, mask_out);
  fused_all<<<(BS * T_FR) / FPB, 256, 0, stream>>>(
      emb, dur, log_sigma, x, mask_out);
}

// Round 8
// 167.046 us; speedup vs baseline: 1.1651x; 1.1651x over previous
//
#include <hip/hip_runtime.h>
#include <math.h>

// Problem constants (fixed instance: bs=32, S=512, E=512, T=2048)
#define BS 32
#define S_TOK 512
#define E_DIM 512
#define T_FR 2048
#define FPB 8           // frames per output block (R4-best structure)
#define WMAX 20         // union-window clamp for 8 frames (typ ~6-11)
// exp cut: dropped softmax terms < e^-25 of the max term (output perturbation
// ~1e-10 abs; absmax 0.0156 is the bf16-grain ref-rounding floor).
#define THRESH -25.0f

// NOTE: durations never zero -> reference's MASK_FILL branch is identity.

// ROUND 7 POST-MORTEM (decomposition probe): double-launch dur = 194.6 ->
// K = 194.6 - 165.6 = 29.0us marginal kernel cost. Pre-committed rule K<=55
// hit: the kernel is AT its ~30us traffic floor (134MB write + 67MB read @
// ~6.8TB/s; warm-L2 second pass write-dominated ~= 29us observed).
// Iteration accounting: ~79us harness poison fill (every top-5 entry) +
// ~45-55us reset() restore dispatches & launch gaps (the ~20KB, 0.25GB/s
// fillBuffer entries in top-5) + ~30-40us kernel AT FLOOR. The 2x "gap"
// chased in R1-R6 was harness cost, not kernel stall — consistent with all
// six structural changes moving the total by only +-2-15us.
// THIS ROUND: revert to the exact R4 single-launch kernel. Roofline declared
// next round with this accounting.

typedef float vfloat4 __attribute__((ext_vector_type(4)));

__global__ __launch_bounds__(256, 8) void fused_all(
    const float* __restrict__ emb,
    const float* __restrict__ dur,
    const float* __restrict__ log_sigma,
    float* __restrict__ x,
    float* __restrict__ mask_out) {
  // XCD swizzle: 8192 blocks; id&7 = XCD slot -> 1024 contiguous-t blocks
  // per XCD = 4 whole batches (4 MB emb slice = its L2).
  int id = blockIdx.x;
  int sw = ((id & 7) << 10) + (id >> 3);
  int b = sw >> 8;             // 256 blocks per batch
  int t0 = (sw & 255) << 3;    // * FPB

  int tid = threadIdx.x;
  int grp = tid >> 7;          // frame group: 0 -> frames t0+0..3, 1 -> t0+4..7
  int col = tid & 127;         // vfloat4 column owner (E_DIM/4 = 128)

  __shared__ float cbS[S_TOK];               // centers, 2 KB
  __shared__ __align__(16) float wT[WMAX][FPB];  // raw exp weights, 640 B
  __shared__ float mS[FPB];                  // per-frame max
  __shared__ float invS[FPB];                // per-frame 1/sum
  __shared__ double wsumS[4];
  __shared__ int histS[FPB];                 // bucket f = #centers in [tq_{f-1},tq_f)
  __shared__ int n0S[4];                     // per-wave partials of count(c < tq0)
  __shared__ int uloS, cntS;
  __shared__ float totalS;

  if (tid < FPB) histS[tid] = 0;

  float inv_sigma = expf(-log_sigma[0]);
  float tq0 = (float)t0 + 0.5f;
  float tq7 = (float)t0 + 7.5f;

  // ---- stage 1: fp64 cumsum of this batch's durations (redundant/block) ----
  {
    const float* dp = dur + b * S_TOK;
    int i2 = tid << 1;
    double d0 = (double)dp[i2];
    double d1 = (double)dp[i2 + 1];
    double pair = d0 + d1;
    double run = pair;                  // wave-inclusive scan of pair sums
#pragma unroll
    for (int off = 1; off < 64; off <<= 1) {
      double v = __shfl_up(run, off, 64);
      if ((tid & 63) >= off) run += v;
    }
    int w = tid >> 6;
    if ((tid & 63) == 63) wsumS[w] = run;
    __syncthreads();   // covers wsumS AND histS zero-init
    double wexcl = 0.0;
#pragma unroll
    for (int k = 0; k < 3; ++k) wexcl += (k < w) ? wsumS[k] : 0.0;
    double incl = wexcl + run;          // inclusive cumsum through this pair
    double excl = incl - pair;          // exclusive before this pair
    float c0 = (float)(excl + d0 - 0.5 * d0);
    float c1 = (float)(excl + (d0 + d1) - 0.5 * d1);
    cbS[i2] = c0;
    cbS[i2 + 1] = c1;

    // insertion-index machinery: N_f = count(c < tq_f) = N0 + prefix_hist.
    // Only in-range centers (~2-3 per block) touch atomics.
    int n0 = (c0 < tq0 ? 1 : 0) + (c1 < tq0 ? 1 : 0);
    if (c0 >= tq0 && c0 < tq7) atomicAdd(&histS[(int)floorf(c0 - tq0) + 1], 1);
    if (c1 >= tq0 && c1 < tq7) atomicAdd(&histS[(int)floorf(c1 - tq0) + 1], 1);
#pragma unroll
    for (int off = 1; off < 64; off <<= 1) n0 += __shfl_xor(n0, off, 64);
    if ((tid & 63) == 0) n0S[w] = n0;
    if (tid == 255) totalS = (float)incl;
  }
  __syncthreads();   // cbS, histS, n0S ready

  // ---- stage 2 (wave 0, fully parallel) ----
  if (tid < 64) {
    int l = tid;
    // inclusive scan of hist over lanes 0..7 (lane 0 -> 0)
    int sc = (l >= 1 && l < FPB) ? histS[l] : 0;
#pragma unroll
    for (int off = 1; off < FPB; off <<= 1) {
      int v = __shfl_up(sc, off, 64);
      if (l >= off) sc += v;
    }
    int N0 = n0S[0] + n0S[1] + n0S[2] + n0S[3];
    int best = 0;
    float m = 0.0f;
    if (l < FPB) {
      int N = N0 + sc;             // insertion index for frame l
      float tqf = (float)(t0 + l) + 0.5f;
      if (N <= 0) {
        best = 0;
        float z = (tqf - cbS[0]) * inv_sigma; m = -0.5f * z * z;
      } else if (N >= S_TOK) {
        best = S_TOK - 1;
        float z = (tqf - cbS[best]) * inv_sigma; m = -0.5f * z * z;
      } else {
        float za = (tqf - cbS[N - 1]) * inv_sigma; float va = -0.5f * za * za;
        float zb = (tqf - cbS[N]) * inv_sigma;     float vb = -0.5f * zb * zb;
        if (va >= vb) { best = N - 1; m = va; } else { best = N; m = vb; }
      }
      mS[l] = m;
    }
    // union window edges: frame 0 lower, frame 7 upper (edges monotone in f);
    // 16-lane ballot probe each (extent ~2-3 tokens; flags monotone).
    int best0 = __shfl(best, 0, 64);  float m0 = __shfl(m, 0, 64);
    int best7 = __shfl(best, 7, 64);  float m7 = __shfl(m, 7, 64);
    int p = l & 15;
    bool flag = false;
    if (l < 16) {
      int s = best0 - 1 - p;
      if (s >= 0) {
        float z = (tq0 - cbS[s]) * inv_sigma;
        flag = (-0.5f * z * z) > m0 + THRESH;
      }
    } else if (l < 32) {
      int s = best7 + 1 + p;
      if (s < S_TOK) {
        float z = (tq7 - cbS[s]) * inv_sigma;
        flag = (-0.5f * z * z) > m7 + THRESH;
      }
    }
    unsigned long long bal = __ballot(flag);
    if (l == 0) {
      int wl = best0 - __popcll(bal & 0xFFFFull);
      int wh = best7 + __popcll(bal & 0xFFFF0000ull);
      uloS = wl;
      cntS = min(wh - wl + 1, WMAX);  // clamp = memory-safety only
    }
  }
  __syncthreads();

  int ulo = uloS, cnt = cntS;

  // prefetch first two emb rows NOW; latency hides under the weights pass
  const vfloat4* e4 =
      (const vfloat4*)emb + ((size_t)(b * S_TOK + ulo)) * (E_DIM / 4) + col;
  vfloat4 vcur = e4[0];
  vfloat4 vnext = e4[(size_t)min(1, cnt - 1) * (E_DIM / 4)];

  // ---- weights: raw exp(v - m_f); cnt*8 <= 160 items -> single pass ----
  if (tid < cnt * FPB) {
    int i = tid >> 3, f = tid & 7;
    float c = cbS[ulo + i];
    float tqf = (float)(t0 + f) + 0.5f;
    float z = (tqf - c) * inv_sigma;
    float v = -0.5f * z * z;
    wT[i][f] = expf(v - mS[f]);   // v<=m always -> exp in (0,1]
  }
  __syncthreads();

  // ---- per-frame sums (32 lanes per frame), 1/l into invS ----
  {
    int f = tid >> 5, p = tid & 31;
    float s = 0.0f;
    for (int i = p; i < cnt; i += 32) s += wT[i][f];
#pragma unroll
    for (int off = 1; off < 32; off <<= 1) s += __shfl_xor(s, off, 64);
    if (p == 0) invS[f] = 1.0f / s;   // s >= exp(0)=1 (best token in union)
  }
  __syncthreads();

  // ---- sparse weighted sum: 4 vfloat4 accumulators, depth-2 prefetch ----
  vfloat4 acc0 = {0.f,0.f,0.f,0.f}, acc1 = {0.f,0.f,0.f,0.f};
  vfloat4 acc2 = {0.f,0.f,0.f,0.f}, acc3 = {0.f,0.f,0.f,0.f};

  for (int i = 0; i < cnt; ++i) {
    vfloat4 vfut = e4[(size_t)min(i + 2, cnt - 1) * (E_DIM / 4)];
    vfloat4 w = *(const vfloat4*)&wT[i][grp << 2];  // broadcast read
    acc0 += w.x * vcur;
    acc1 += w.y * vcur;
    acc2 += w.z * vcur;
    acc3 += w.w * vcur;
    vcur = vnext; vnext = vfut;
  }

  // Regular cached stores; normalization (1/l_f) folded in here.
  int f0 = grp << 2;
  vfloat4* xp = (vfloat4*)x +
      ((size_t)(b * T_FR + t0 + f0)) * (E_DIM / 4) + col;
  xp[0 * (E_DIM / 4)] = acc0 * invS[f0 + 0];
  xp[1 * (E_DIM / 4)] = acc1 * invS[f0 + 1];
  xp[2 * (E_DIM / 4)] = acc2 * invS[f0 + 2];
  xp[3 * (E_DIM / 4)] = acc3 * invS[f0 + 3];

  if (tid < FPB) {
    int t = t0 + tid;
    mask_out[b * T_FR + t] = ((float)t < totalS) ? 1.0f : 0.0f;
  }
}

// ---------------------------------------------------------------------------
extern "C" void kernel_launch(void* const* d_in, const int* in_sizes, int n_in,
                              void* d_out, int out_size, void* d_ws,
                              size_t ws_size, hipStream_t stream) {
  const float* emb = (const float*)d_in[0];        // (32, 512, 512)
  const float* dur = (const float*)d_in[1];        // (32, 512)
  const float* log_sigma = (const float*)d_in[2];  // (1,)

  float* x = (float*)d_out;                         // (32, 2048, 512)
  float* mask_out = x + (size_t)BS * T_FR * E_DIM;  // (32, 2048)

  fused_all<<<(BS * T_FR) / FPB, 256, 0, stream>>>(
      emb, dur, log_sigma, x, mask_out);
}